// Round 10
// baseline (1189.901 us; speedup 1.0000x reference)
//
#include <hip/hip_runtime.h>

#define THREADS 256
#define SCAN_CHUNK 2048
#define DT_C 0.2f

__device__ __forceinline__ unsigned pack_bf16(float x, float y) {
    unsigned xb = __float_as_uint(x);
    unsigned yb = __float_as_uint(y);
    xb = (xb + 0x7fffu + ((xb >> 16) & 1u)) >> 16;
    yb = (yb + 0x7fffu + ((yb >> 16) & 1u)) >> 16;
    return xb | (yb << 16);
}
__device__ __forceinline__ float lo16(unsigned u) { return __uint_as_float(u << 16); }
__device__ __forceinline__ float hi16(unsigned u) { return __uint_as_float(u & 0xffff0000u); }

// ---------------- CSR build ----------------

__global__ void count_deg_kernel(const int* __restrict__ ei, int E,
                                 int* __restrict__ deg_r, int* __restrict__ deg_c) {
    int e = blockIdx.x * blockDim.x + threadIdx.x;
    if (e < E) {
        atomicAdd(&deg_r[ei[e]], 1);
        atomicAdd(&deg_c[ei[e + E]], 1);
    }
}

__global__ void scan_phase1(const int* __restrict__ deg, int n, int* __restrict__ bsums) {
    int base = blockIdx.x * SCAN_CHUNK;
    int sum = 0;
    for (int i = threadIdx.x; i < SCAN_CHUNK; i += THREADS) {
        int idx = base + i;
        if (idx < n) sum += deg[idx];
    }
    __shared__ int wsum[4];
    int lane = threadIdx.x & 63, wid = threadIdx.x >> 6;
    for (int off = 32; off; off >>= 1) sum += __shfl_down(sum, off);
    if (lane == 0) wsum[wid] = sum;
    __syncthreads();
    if (threadIdx.x == 0)
        bsums[blockIdx.x] = wsum[0] + wsum[1] + wsum[2] + wsum[3];
}

__global__ void scan_phase2(int* __restrict__ bsums, int nb,
                            int* __restrict__ row_ptr, int N, int E) {
    if (blockIdx.x == 0 && threadIdx.x == 0) {
        int acc = 0;
        for (int b = 0; b < nb; ++b) { int v = bsums[b]; bsums[b] = acc; acc += v; }
        row_ptr[N] = E;
    }
}

__global__ void scan_phase3(const int* __restrict__ deg, int n, const int* __restrict__ bsums,
                            int* __restrict__ row_ptr, int* __restrict__ cur_f,
                            int* __restrict__ cur_b) {
    int base = blockIdx.x * SCAN_CHUNK;
    int tbase = base + threadIdx.x * 8;
    int my[8]; int s = 0;
#pragma unroll
    for (int j = 0; j < 8; ++j) { int idx = tbase + j; my[j] = (idx < n) ? deg[idx] : 0; s += my[j]; }
    int lane = threadIdx.x & 63, wid = threadIdx.x >> 6;
    int v = s;
    for (int off = 1; off < 64; off <<= 1) { int t = __shfl_up(v, off); if (lane >= off) v += t; }
    __shared__ int wsum[4];
    if (lane == 63) wsum[wid] = v;
    __syncthreads();
    int woff = 0;
    for (int w = 0; w < wid; ++w) woff += wsum[w];
    int acc = bsums[blockIdx.x] + woff + (v - s);
#pragma unroll
    for (int j = 0; j < 8; ++j) {
        int idx = tbase + j;
        if (idx < n) { row_ptr[idx] = acc; cur_f[idx] = acc; cur_b[idx] = acc + my[j]; }
        acc += my[j];
    }
}

// dr = deg_r^-1/2, dc = deg_c^-1/2, s1 = dr*dc (combined epilogue scale)
__global__ void make_dinv(const int* __restrict__ deg_r, const int* __restrict__ deg_c,
                          float* __restrict__ dr, float* __restrict__ dc,
                          float* __restrict__ s1, int n) {
    int i = blockIdx.x * blockDim.x + threadIdx.x;
    if (i < n) {
        int ra = deg_r[i];
        float a = ra > 0 ? rsqrtf((float)ra) : 0.f;
        int cb = deg_c[i];
        float b = cb > 0 ? rsqrtf((float)cb) : 0.f;
        dr[i] = a; dc[i] = b; s1[i] = a * b;
    }
}

// Partitioned scatter: masked edges from the row front, unmasked from the back.
// cur_f[r] ends as the split point.
__global__ void build_csr_kernel(const int* __restrict__ ei, int E,
                                 const int* __restrict__ mask,
                                 int* __restrict__ cur_f, int* __restrict__ cur_b,
                                 int* __restrict__ colv) {
    int e = blockIdx.x * blockDim.x + threadIdx.x;
    if (e < E) {
        int r = ei[e], c = ei[e + E];
        int p;
        if (mask[c]) p = atomicAdd(&cur_f[r], 1);
        else         p = atomicSub(&cur_b[r], 1) - 1;
        colv[p] = c;
    }
}

// ---------------- init: out[0] = r0 ; xb = bf16(dc .* r0) ----------------

__global__ void init_kernel(const float* __restrict__ r0, float* __restrict__ out0,
                            const float* __restrict__ dc,
                            unsigned* __restrict__ xb, int n4) {
    int i = blockIdx.x * blockDim.x + threadIdx.x;
    int stride = gridDim.x * blockDim.x;
    const float4* r4 = (const float4*)r0;
    float4* o4 = (float4*)out0;
    for (; i < n4; i += stride) {
        float4 a = r4[i];
        o4[i] = a;
        float w = dc[i >> 4];   // 16 float4s per node
        xb[2 * i]     = pack_bf16(w * a.x, w * a.y);
        xb[2 * i + 1] = pack_bf16(w * a.z, w * a.w);
    }
}

// ---------------- SpMM hop 1 ----------------
// Gathers bf16(dc .* x) over the masked front segment; pure gather-add
// (weights pre-folded into the payload). t1b = bf16(s1[row] * sum).
// Unroll-8 = eight consecutive pair statements (bit-identical accumulation
// order to the r6 engine); tail cascades 8 -> 4 -> pair -> single.

__global__ __launch_bounds__(256) void spmm_h1(const int* __restrict__ row_ptr,
                                               const int* __restrict__ split,
                                               const int* __restrict__ cols,
                                               const float* __restrict__ s1,
                                               const unsigned* __restrict__ xb,
                                               unsigned* __restrict__ t1b, int n) {
    int row = blockIdx.x * 4 + (threadIdx.x >> 6);
    if (row >= n) return;
    int l = threadIdx.x & 63, h = l >> 5, hl = l & 31;
    int s = row_ptr[row], e = split[row];
    float a0 = 0.f, a1 = 0.f;
    int j = s + h;
    for (; j + 30 < e; j += 32) {
        int c0 = cols[j],      c1 = cols[j + 2],  c2 = cols[j + 4],  c3 = cols[j + 6];
        int c4 = cols[j + 8],  c5 = cols[j + 10], c6 = cols[j + 12], c7 = cols[j + 14];
        int c8 = cols[j + 16], c9 = cols[j + 18], ca = cols[j + 20], cb = cols[j + 22];
        int cc = cols[j + 24], cd = cols[j + 26], ce = cols[j + 28], cf = cols[j + 30];
        unsigned u0 = xb[c0 * 32 + hl], u1 = xb[c1 * 32 + hl];
        unsigned u2 = xb[c2 * 32 + hl], u3 = xb[c3 * 32 + hl];
        unsigned u4 = xb[c4 * 32 + hl], u5 = xb[c5 * 32 + hl];
        unsigned u6 = xb[c6 * 32 + hl], u7 = xb[c7 * 32 + hl];
        unsigned u8 = xb[c8 * 32 + hl], u9 = xb[c9 * 32 + hl];
        unsigned ua = xb[ca * 32 + hl], ub = xb[cb * 32 + hl];
        unsigned uc = xb[cc * 32 + hl], ud = xb[cd * 32 + hl];
        unsigned ue = xb[ce * 32 + hl], uf = xb[cf * 32 + hl];
        a0 += lo16(u0) + lo16(u1);  a1 += hi16(u0) + hi16(u1);
        a0 += lo16(u2) + lo16(u3);  a1 += hi16(u2) + hi16(u3);
        a0 += lo16(u4) + lo16(u5);  a1 += hi16(u4) + hi16(u5);
        a0 += lo16(u6) + lo16(u7);  a1 += hi16(u6) + hi16(u7);
        a0 += lo16(u8) + lo16(u9);  a1 += hi16(u8) + hi16(u9);
        a0 += lo16(ua) + lo16(ub);  a1 += hi16(ua) + hi16(ub);
        a0 += lo16(uc) + lo16(ud);  a1 += hi16(uc) + hi16(ud);
        a0 += lo16(ue) + lo16(uf);  a1 += hi16(ue) + hi16(uf);
    }
    for (; j + 14 < e; j += 16) {
        int c0 = cols[j],     c1 = cols[j + 2],  c2 = cols[j + 4],  c3 = cols[j + 6];
        int c4 = cols[j + 8], c5 = cols[j + 10], c6 = cols[j + 12], c7 = cols[j + 14];
        unsigned u0 = xb[c0 * 32 + hl], u1 = xb[c1 * 32 + hl];
        unsigned u2 = xb[c2 * 32 + hl], u3 = xb[c3 * 32 + hl];
        unsigned u4 = xb[c4 * 32 + hl], u5 = xb[c5 * 32 + hl];
        unsigned u6 = xb[c6 * 32 + hl], u7 = xb[c7 * 32 + hl];
        a0 += lo16(u0) + lo16(u1);  a1 += hi16(u0) + hi16(u1);
        a0 += lo16(u2) + lo16(u3);  a1 += hi16(u2) + hi16(u3);
        a0 += lo16(u4) + lo16(u5);  a1 += hi16(u4) + hi16(u5);
        a0 += lo16(u6) + lo16(u7);  a1 += hi16(u6) + hi16(u7);
    }
    for (; j + 2 < e; j += 4) {
        int c0 = cols[j], c1 = cols[j + 2];
        unsigned u0 = xb[c0 * 32 + hl], u1 = xb[c1 * 32 + hl];
        a0 += lo16(u0) + lo16(u1);  a1 += hi16(u0) + hi16(u1);
    }
    if (j < e) {
        unsigned u0 = xb[cols[j] * 32 + hl];
        a0 += lo16(u0);  a1 += hi16(u0);
    }
    a0 += __shfl_xor(a0, 32);
    a1 += __shfl_xor(a1, 32);
    if (l < 32) {
        float w = s1[row];
        t1b[row * 32 + hl] = pack_bf16(w * a0, w * a1);
    }
}

// ---------------- SpMM hop 2 + fused Taylor epilogue ----------------
// a = sum t1b[col] over the FULL segment (dc pre-folded into t1b).
// k = -dr[row] * a.
// ST==0 (first): rn = r + g*k ; xb = bf16(dc*k) = bf16(-s1*a)  [masked rows]
// ST==3 (last):  rn += g*k    ; xb = bf16(dc*rn)               [masked rows]

template <int ST>
__global__ __launch_bounds__(256) void spmm_h2(const int* __restrict__ row_ptr,
                                               const int* __restrict__ cols,
                                               const float* __restrict__ dr_arr,
                                               const float* __restrict__ dc_arr,
                                               const float* __restrict__ s1,
                                               const int* __restrict__ msk,
                                               const unsigned* __restrict__ t1b,
                                               const float* __restrict__ r_prev,
                                               float* __restrict__ rn,
                                               unsigned* __restrict__ xb,
                                               float g, int n) {
    int row = blockIdx.x * 4 + (threadIdx.x >> 6);
    if (row >= n) return;
    int l = threadIdx.x & 63, h = l >> 5, hl = l & 31;
    int s = row_ptr[row], e = row_ptr[row + 1];
    float a0 = 0.f, a1 = 0.f;
    int j = s + h;
    for (; j + 30 < e; j += 32) {
        int c0 = cols[j],      c1 = cols[j + 2],  c2 = cols[j + 4],  c3 = cols[j + 6];
        int c4 = cols[j + 8],  c5 = cols[j + 10], c6 = cols[j + 12], c7 = cols[j + 14];
        int c8 = cols[j + 16], c9 = cols[j + 18], ca = cols[j + 20], cb = cols[j + 22];
        int cc = cols[j + 24], cd = cols[j + 26], ce = cols[j + 28], cf = cols[j + 30];
        unsigned u0 = t1b[c0 * 32 + hl], u1 = t1b[c1 * 32 + hl];
        unsigned u2 = t1b[c2 * 32 + hl], u3 = t1b[c3 * 32 + hl];
        unsigned u4 = t1b[c4 * 32 + hl], u5 = t1b[c5 * 32 + hl];
        unsigned u6 = t1b[c6 * 32 + hl], u7 = t1b[c7 * 32 + hl];
        unsigned u8 = t1b[c8 * 32 + hl], u9 = t1b[c9 * 32 + hl];
        unsigned ua = t1b[ca * 32 + hl], ub = t1b[cb * 32 + hl];
        unsigned uc = t1b[cc * 32 + hl], ud = t1b[cd * 32 + hl];
        unsigned ue = t1b[ce * 32 + hl], uf = t1b[cf * 32 + hl];
        a0 += lo16(u0) + lo16(u1);  a1 += hi16(u0) + hi16(u1);
        a0 += lo16(u2) + lo16(u3);  a1 += hi16(u2) + hi16(u3);
        a0 += lo16(u4) + lo16(u5);  a1 += hi16(u4) + hi16(u5);
        a0 += lo16(u6) + lo16(u7);  a1 += hi16(u6) + hi16(u7);
        a0 += lo16(u8) + lo16(u9);  a1 += hi16(u8) + hi16(u9);
        a0 += lo16(ua) + lo16(ub);  a1 += hi16(ua) + hi16(ub);
        a0 += lo16(uc) + lo16(ud);  a1 += hi16(uc) + hi16(ud);
        a0 += lo16(ue) + lo16(uf);  a1 += hi16(ue) + hi16(uf);
    }
    for (; j + 14 < e; j += 16) {
        int c0 = cols[j],     c1 = cols[j + 2],  c2 = cols[j + 4],  c3 = cols[j + 6];
        int c4 = cols[j + 8], c5 = cols[j + 10], c6 = cols[j + 12], c7 = cols[j + 14];
        unsigned u0 = t1b[c0 * 32 + hl], u1 = t1b[c1 * 32 + hl];
        unsigned u2 = t1b[c2 * 32 + hl], u3 = t1b[c3 * 32 + hl];
        unsigned u4 = t1b[c4 * 32 + hl], u5 = t1b[c5 * 32 + hl];
        unsigned u6 = t1b[c6 * 32 + hl], u7 = t1b[c7 * 32 + hl];
        a0 += lo16(u0) + lo16(u1);  a1 += hi16(u0) + hi16(u1);
        a0 += lo16(u2) + lo16(u3);  a1 += hi16(u2) + hi16(u3);
        a0 += lo16(u4) + lo16(u5);  a1 += hi16(u4) + hi16(u5);
        a0 += lo16(u6) + lo16(u7);  a1 += hi16(u6) + hi16(u7);
    }
    for (; j + 2 < e; j += 4) {
        int c0 = cols[j], c1 = cols[j + 2];
        unsigned u0 = t1b[c0 * 32 + hl], u1 = t1b[c1 * 32 + hl];
        a0 += lo16(u0) + lo16(u1);  a1 += hi16(u0) + hi16(u1);
    }
    if (j < e) {
        unsigned u0 = t1b[cols[j] * 32 + hl];
        a0 += lo16(u0);  a1 += hi16(u0);
    }
    a0 += __shfl_xor(a0, 32);
    a1 += __shfl_xor(a1, 32);
    if (l < 32) {
        float dr_ = dr_arr[row];
        float k0 = -dr_ * a0, k1 = -dr_ * a1;
        int idx = row * 32 + hl;
        const float2* r2 = (const float2*)r_prev;
        float2* rn2 = (float2*)rn;
        bool m = msk[row] != 0;   // xb only ever gathered for masked rows
        if (ST == 0) {
            float2 rv = r2[idx];
            rn2[idx] = make_float2(rv.x + g * k0, rv.y + g * k1);
            if (m) {
                float w = s1[row];
                xb[idx] = pack_bf16(-w * a0, -w * a1);   // dc*k
            }
        } else {
            float2 p = rn2[idx];
            p.x += g * k0; p.y += g * k1;
            rn2[idx] = p;
            if (m) {
                float dc_ = dc_arr[row];
                xb[idx] = pack_bf16(dc_ * p.x, dc_ * p.y);
            }
        }
    }
}

// ---------------- host ----------------

extern "C" void kernel_launch(void* const* d_in, const int* in_sizes, int n_in,
                              void* d_out, int out_size, void* d_ws, size_t ws_size,
                              hipStream_t stream) {
    const float* r0  = (const float*)d_in[0];
    const int*   ei  = (const int*)d_in[1];
    const int*   msk = (const int*)d_in[2];
    float* out = (float*)d_out;

    const int N = in_sizes[2];
    const int E = in_sizes[1] / 2;
    const size_t ND = (size_t)N * 64;

    char* ws = (char*)d_ws;
    size_t off = 0;
    auto carve = [&](size_t bytes) -> void* {
        off = (off + 255) & ~(size_t)255;
        void* p = ws + off;
        off += bytes;
        return p;
    };
    int*      deg_r   = (int*)carve((size_t)N * 4);
    int*      deg_c   = (int*)carve((size_t)N * 4);
    int*      row_ptr = (int*)carve((size_t)(N + 1) * 4);
    int*      cur_f   = (int*)carve((size_t)N * 4);   // front cursor -> split point
    int*      cur_b   = (int*)carve((size_t)N * 4);   // back cursor
    int*      bsums   = (int*)carve(1024 * 4);
    float*    dr      = (float*)carve((size_t)N * 4);
    float*    dc      = (float*)carve((size_t)N * 4);
    float*    s1      = (float*)carve((size_t)N * 4);
    int*      colv    = (int*)carve((size_t)E * 4);
    unsigned* xb      = (unsigned*)carve((size_t)N * 32 * 4);
    unsigned* t1b     = (unsigned*)carve((size_t)N * 32 * 4);

    // ---- CSR build (edges partitioned [masked | unmasked] within each row) ----
    hipMemsetAsync(deg_r, 0, (size_t)N * 4, stream);
    hipMemsetAsync(deg_c, 0, (size_t)N * 4, stream);
    int gE = (E + THREADS - 1) / THREADS;
    count_deg_kernel<<<gE, THREADS, 0, stream>>>(ei, E, deg_r, deg_c);
    int nb = (N + SCAN_CHUNK - 1) / SCAN_CHUNK;
    scan_phase1<<<nb, THREADS, 0, stream>>>(deg_r, N, bsums);
    scan_phase2<<<1, 64, 0, stream>>>(bsums, nb, row_ptr, N, E);
    scan_phase3<<<nb, THREADS, 0, stream>>>(deg_r, N, bsums, row_ptr, cur_f, cur_b);
    make_dinv<<<(N + THREADS - 1) / THREADS, THREADS, 0, stream>>>(deg_r, deg_c, dr, dc, s1, N);
    build_csr_kernel<<<gE, THREADS, 0, stream>>>(ei, E, msk, cur_f, cur_b, colv);

    // ---- out[0] = r0 ; xb = bf16(dc .* r0) ----
    init_kernel<<<2048, THREADS, 0, stream>>>(r0, out, dc, xb, (int)(ND / 4));

    // ---- 5 steps of degree-2 Taylor: r+ = r + g1*Lr + g2*L^2 r ----
    const float g[2] = {DT_C, DT_C * DT_C / 2.f};
    int gridR = (N + 3) / 4;

    for (int s = 0; s < 5; ++s) {
        const float* r  = out + (size_t)s * ND;
        float*       rn = out + (size_t)(s + 1) * ND;
        for (int st = 0; st < 2; ++st) {
            spmm_h1<<<gridR, THREADS, 0, stream>>>(row_ptr, cur_f, colv, s1, xb, t1b, N);
            if (st == 0)
                spmm_h2<0><<<gridR, THREADS, 0, stream>>>(row_ptr, colv, dr, dc, s1, msk, t1b, r, rn, xb, g[st], N);
            else
                spmm_h2<3><<<gridR, THREADS, 0, stream>>>(row_ptr, colv, dr, dc, s1, msk, t1b, r, rn, xb, g[st], N);
        }
    }
}

// Round 11
// 1100.812 us; speedup vs baseline: 1.0809x; 1.0809x over previous
//
#include <hip/hip_runtime.h>

#define THREADS 256
#define SCAN_CHUNK 2048
#define DT_C 0.2f

__device__ __forceinline__ unsigned pack_bf16(float x, float y) {
    unsigned xb = __float_as_uint(x);
    unsigned yb = __float_as_uint(y);
    xb = (xb + 0x7fffu + ((xb >> 16) & 1u)) >> 16;
    yb = (yb + 0x7fffu + ((yb >> 16) & 1u)) >> 16;
    return xb | (yb << 16);
}
__device__ __forceinline__ float lo16(unsigned u) { return __uint_as_float(u << 16); }
__device__ __forceinline__ float hi16(unsigned u) { return __uint_as_float(u & 0xffff0000u); }

// ---------------- CSR build ----------------

__global__ void count_deg_kernel(const int* __restrict__ ei, int E,
                                 int* __restrict__ deg_r, int* __restrict__ deg_c) {
    int e = blockIdx.x * blockDim.x + threadIdx.x;
    if (e < E) {
        atomicAdd(&deg_r[ei[e]], 1);
        atomicAdd(&deg_c[ei[e + E]], 1);
    }
}

__global__ void scan_phase1(const int* __restrict__ deg, int n, int* __restrict__ bsums) {
    int base = blockIdx.x * SCAN_CHUNK;
    int sum = 0;
    for (int i = threadIdx.x; i < SCAN_CHUNK; i += THREADS) {
        int idx = base + i;
        if (idx < n) sum += deg[idx];
    }
    __shared__ int wsum[4];
    int lane = threadIdx.x & 63, wid = threadIdx.x >> 6;
    for (int off = 32; off; off >>= 1) sum += __shfl_down(sum, off);
    if (lane == 0) wsum[wid] = sum;
    __syncthreads();
    if (threadIdx.x == 0)
        bsums[blockIdx.x] = wsum[0] + wsum[1] + wsum[2] + wsum[3];
}

__global__ void scan_phase2(int* __restrict__ bsums, int nb,
                            int* __restrict__ row_ptr, int N, int E) {
    if (blockIdx.x == 0 && threadIdx.x == 0) {
        int acc = 0;
        for (int b = 0; b < nb; ++b) { int v = bsums[b]; bsums[b] = acc; acc += v; }
        row_ptr[N] = E;
    }
}

__global__ void scan_phase3(const int* __restrict__ deg, int n, const int* __restrict__ bsums,
                            int* __restrict__ row_ptr, int* __restrict__ cur_f,
                            int* __restrict__ cur_b) {
    int base = blockIdx.x * SCAN_CHUNK;
    int tbase = base + threadIdx.x * 8;
    int my[8]; int s = 0;
#pragma unroll
    for (int j = 0; j < 8; ++j) { int idx = tbase + j; my[j] = (idx < n) ? deg[idx] : 0; s += my[j]; }
    int lane = threadIdx.x & 63, wid = threadIdx.x >> 6;
    int v = s;
    for (int off = 1; off < 64; off <<= 1) { int t = __shfl_up(v, off); if (lane >= off) v += t; }
    __shared__ int wsum[4];
    if (lane == 63) wsum[wid] = v;
    __syncthreads();
    int woff = 0;
    for (int w = 0; w < wid; ++w) woff += wsum[w];
    int acc = bsums[blockIdx.x] + woff + (v - s);
#pragma unroll
    for (int j = 0; j < 8; ++j) {
        int idx = tbase + j;
        if (idx < n) { row_ptr[idx] = acc; cur_f[idx] = acc; cur_b[idx] = acc + my[j]; }
        acc += my[j];
    }
}

// dr = deg_r^-1/2, dc = deg_c^-1/2, s1 = dr*dc
__global__ void make_dinv(const int* __restrict__ deg_r, const int* __restrict__ deg_c,
                          float* __restrict__ dr, float* __restrict__ dc,
                          float* __restrict__ s1, int n) {
    int i = blockIdx.x * blockDim.x + threadIdx.x;
    if (i < n) {
        int ra = deg_r[i];
        float a = ra > 0 ? rsqrtf((float)ra) : 0.f;
        int cb = deg_c[i];
        float b = cb > 0 ? rsqrtf((float)cb) : 0.f;
        dr[i] = a; dc[i] = b; s1[i] = a * b;
    }
}

// Partitioned scatter: masked edges from the row front, unmasked from the back.
// cur_f[r] ends as the split point.
__global__ void build_csr_kernel(const int* __restrict__ ei, int E,
                                 const int* __restrict__ mask,
                                 int* __restrict__ cur_f, int* __restrict__ cur_b,
                                 int* __restrict__ colv) {
    int e = blockIdx.x * blockDim.x + threadIdx.x;
    if (e < E) {
        int r = ei[e], c = ei[e + E];
        int p;
        if (mask[c]) p = atomicAdd(&cur_f[r], 1);
        else         p = atomicSub(&cur_b[r], 1) - 1;
        colv[p] = c;
    }
}

// ---------------- init: out[0] = r0 ; xb = bf16(dc .* r0) ----------------

__global__ void init_kernel(const float* __restrict__ r0, float* __restrict__ out0,
                            const float* __restrict__ dc,
                            unsigned* __restrict__ xb, int n4) {
    int i = blockIdx.x * blockDim.x + threadIdx.x;
    int stride = gridDim.x * blockDim.x;
    const float4* r4 = (const float4*)r0;
    float4* o4 = (float4*)out0;
    for (; i < n4; i += stride) {
        float4 a = r4[i];
        o4[i] = a;
        float w = dc[i >> 4];   // 16 float4s per node
        xb[2 * i]     = pack_bf16(w * a.x, w * a.y);
        xb[2 * i + 1] = pack_bf16(w * a.z, w * a.w);
    }
}

// ---------------- SpMM hop 1 ----------------
// Gathers bf16(dc .* x) over the masked front segment; pure gather-add.
// r9 cascade: 16/8/4/1-edge levels (matched to Poisson(8) masked segments).
// t1b = bf16(s1[row] * sum).

__global__ __launch_bounds__(256) void spmm_h1(const int* __restrict__ row_ptr,
                                               const int* __restrict__ split,
                                               const int* __restrict__ cols,
                                               const float* __restrict__ s1,
                                               const unsigned* __restrict__ xb,
                                               unsigned* __restrict__ t1b, int n) {
    int row = blockIdx.x * 4 + (threadIdx.x >> 6);
    if (row >= n) return;
    int l = threadIdx.x & 63, h = l >> 5, hl = l & 31;
    int s = row_ptr[row], e = split[row];
    float a0 = 0.f, a1 = 0.f;
    int j = s + h;
    for (; j + 14 < e; j += 16) {
        int c0 = cols[j],     c1 = cols[j + 2],  c2 = cols[j + 4],  c3 = cols[j + 6];
        int c4 = cols[j + 8], c5 = cols[j + 10], c6 = cols[j + 12], c7 = cols[j + 14];
        unsigned u0 = xb[c0 * 32 + hl], u1 = xb[c1 * 32 + hl];
        unsigned u2 = xb[c2 * 32 + hl], u3 = xb[c3 * 32 + hl];
        unsigned u4 = xb[c4 * 32 + hl], u5 = xb[c5 * 32 + hl];
        unsigned u6 = xb[c6 * 32 + hl], u7 = xb[c7 * 32 + hl];
        a0 += lo16(u0) + lo16(u1);  a1 += hi16(u0) + hi16(u1);
        a0 += lo16(u2) + lo16(u3);  a1 += hi16(u2) + hi16(u3);
        a0 += lo16(u4) + lo16(u5);  a1 += hi16(u4) + hi16(u5);
        a0 += lo16(u6) + lo16(u7);  a1 += hi16(u6) + hi16(u7);
    }
    for (; j + 6 < e; j += 8) {
        int c0 = cols[j], c1 = cols[j + 2], c2 = cols[j + 4], c3 = cols[j + 6];
        unsigned u0 = xb[c0 * 32 + hl], u1 = xb[c1 * 32 + hl];
        unsigned u2 = xb[c2 * 32 + hl], u3 = xb[c3 * 32 + hl];
        a0 += lo16(u0) + lo16(u1);  a1 += hi16(u0) + hi16(u1);
        a0 += lo16(u2) + lo16(u3);  a1 += hi16(u2) + hi16(u3);
    }
    for (; j + 2 < e; j += 4) {
        int c0 = cols[j], c1 = cols[j + 2];
        unsigned u0 = xb[c0 * 32 + hl], u1 = xb[c1 * 32 + hl];
        a0 += lo16(u0) + lo16(u1);  a1 += hi16(u0) + hi16(u1);
    }
    if (j < e) {
        unsigned u0 = xb[cols[j] * 32 + hl];
        a0 += lo16(u0);  a1 += hi16(u0);
    }
    a0 += __shfl_xor(a0, 32);
    a1 += __shfl_xor(a1, 32);
    if (l < 32) {
        float w = s1[row];
        t1b[row * 32 + hl] = pack_bf16(w * a0, w * a1);
    }
}

// ---------------- SpMM hop 2 + fused Taylor epilogue ----------------
// a = sum t1b[col] over the FULL segment (dc pre-folded into t1b); k = -dr*a.
// ST==0 (first): rn = r + g*k ; xb = bf16(dc*k) = bf16(-s1*a)  [masked rows only]
// ST==3 (last):  rn += g*k    ; xb = bf16(dc*rn)               [masked rows only]

template <int ST>
__global__ __launch_bounds__(256) void spmm_h2(const int* __restrict__ row_ptr,
                                               const int* __restrict__ cols,
                                               const float* __restrict__ dr_arr,
                                               const float* __restrict__ dc_arr,
                                               const float* __restrict__ s1,
                                               const int* __restrict__ msk,
                                               const unsigned* __restrict__ t1b,
                                               const float* __restrict__ r_prev,
                                               float* __restrict__ rn,
                                               unsigned* __restrict__ xb,
                                               float g, int n) {
    int row = blockIdx.x * 4 + (threadIdx.x >> 6);
    if (row >= n) return;
    int l = threadIdx.x & 63, h = l >> 5, hl = l & 31;
    int s = row_ptr[row], e = row_ptr[row + 1];
    float a0 = 0.f, a1 = 0.f;
    int j = s + h;
    for (; j + 14 < e; j += 16) {
        int c0 = cols[j],     c1 = cols[j + 2],  c2 = cols[j + 4],  c3 = cols[j + 6];
        int c4 = cols[j + 8], c5 = cols[j + 10], c6 = cols[j + 12], c7 = cols[j + 14];
        unsigned u0 = t1b[c0 * 32 + hl], u1 = t1b[c1 * 32 + hl];
        unsigned u2 = t1b[c2 * 32 + hl], u3 = t1b[c3 * 32 + hl];
        unsigned u4 = t1b[c4 * 32 + hl], u5 = t1b[c5 * 32 + hl];
        unsigned u6 = t1b[c6 * 32 + hl], u7 = t1b[c7 * 32 + hl];
        a0 += lo16(u0) + lo16(u1);  a1 += hi16(u0) + hi16(u1);
        a0 += lo16(u2) + lo16(u3);  a1 += hi16(u2) + hi16(u3);
        a0 += lo16(u4) + lo16(u5);  a1 += hi16(u4) + hi16(u5);
        a0 += lo16(u6) + lo16(u7);  a1 += hi16(u6) + hi16(u7);
    }
    for (; j + 6 < e; j += 8) {
        int c0 = cols[j], c1 = cols[j + 2], c2 = cols[j + 4], c3 = cols[j + 6];
        unsigned u0 = t1b[c0 * 32 + hl], u1 = t1b[c1 * 32 + hl];
        unsigned u2 = t1b[c2 * 32 + hl], u3 = t1b[c3 * 32 + hl];
        a0 += lo16(u0) + lo16(u1);  a1 += hi16(u0) + hi16(u1);
        a0 += lo16(u2) + lo16(u3);  a1 += hi16(u2) + hi16(u3);
    }
    for (; j + 2 < e; j += 4) {
        int c0 = cols[j], c1 = cols[j + 2];
        unsigned u0 = t1b[c0 * 32 + hl], u1 = t1b[c1 * 32 + hl];
        a0 += lo16(u0) + lo16(u1);  a1 += hi16(u0) + hi16(u1);
    }
    if (j < e) {
        unsigned u0 = t1b[cols[j] * 32 + hl];
        a0 += lo16(u0);  a1 += hi16(u0);
    }
    a0 += __shfl_xor(a0, 32);
    a1 += __shfl_xor(a1, 32);
    if (l < 32) {
        float dr_ = dr_arr[row];
        float k0 = -dr_ * a0, k1 = -dr_ * a1;
        int idx = row * 32 + hl;
        const float2* r2 = (const float2*)r_prev;
        float2* rn2 = (float2*)rn;
        bool m = msk[row] != 0;   // xb only ever gathered for masked rows
        if (ST == 0) {
            float2 rv = r2[idx];
            rn2[idx] = make_float2(rv.x + g * k0, rv.y + g * k1);
            if (m) {
                float w = s1[row];
                xb[idx] = pack_bf16(-w * a0, -w * a1);   // dc*k
            }
        } else {
            float2 p = rn2[idx];
            p.x += g * k0; p.y += g * k1;
            rn2[idx] = p;
            if (m) {
                float dc_ = dc_arr[row];
                xb[idx] = pack_bf16(dc_ * p.x, dc_ * p.y);
            }
        }
    }
}

// ---------------- host ----------------

extern "C" void kernel_launch(void* const* d_in, const int* in_sizes, int n_in,
                              void* d_out, int out_size, void* d_ws, size_t ws_size,
                              hipStream_t stream) {
    const float* r0  = (const float*)d_in[0];
    const int*   ei  = (const int*)d_in[1];
    const int*   msk = (const int*)d_in[2];
    float* out = (float*)d_out;

    const int N = in_sizes[2];
    const int E = in_sizes[1] / 2;
    const size_t ND = (size_t)N * 64;

    char* ws = (char*)d_ws;
    size_t off = 0;
    auto carve = [&](size_t bytes) -> void* {
        off = (off + 255) & ~(size_t)255;
        void* p = ws + off;
        off += bytes;
        return p;
    };
    int*      deg_r   = (int*)carve((size_t)N * 4);
    int*      deg_c   = (int*)carve((size_t)N * 4);
    int*      row_ptr = (int*)carve((size_t)(N + 1) * 4);
    int*      cur_f   = (int*)carve((size_t)N * 4);   // front cursor -> split point
    int*      cur_b   = (int*)carve((size_t)N * 4);   // back cursor
    int*      bsums   = (int*)carve(1024 * 4);
    float*    dr      = (float*)carve((size_t)N * 4);
    float*    dc      = (float*)carve((size_t)N * 4);
    float*    s1      = (float*)carve((size_t)N * 4);
    int*      colv    = (int*)carve((size_t)E * 4);
    unsigned* xb      = (unsigned*)carve((size_t)N * 32 * 4);
    unsigned* t1b     = (unsigned*)carve((size_t)N * 32 * 4);

    // ---- CSR build (edges partitioned [masked | unmasked] within each row) ----
    hipMemsetAsync(deg_r, 0, (size_t)N * 4, stream);
    hipMemsetAsync(deg_c, 0, (size_t)N * 4, stream);
    int gE = (E + THREADS - 1) / THREADS;
    count_deg_kernel<<<gE, THREADS, 0, stream>>>(ei, E, deg_r, deg_c);
    int nb = (N + SCAN_CHUNK - 1) / SCAN_CHUNK;
    scan_phase1<<<nb, THREADS, 0, stream>>>(deg_r, N, bsums);
    scan_phase2<<<1, 64, 0, stream>>>(bsums, nb, row_ptr, N, E);
    scan_phase3<<<nb, THREADS, 0, stream>>>(deg_r, N, bsums, row_ptr, cur_f, cur_b);
    make_dinv<<<(N + THREADS - 1) / THREADS, THREADS, 0, stream>>>(deg_r, deg_c, dr, dc, s1, N);
    build_csr_kernel<<<gE, THREADS, 0, stream>>>(ei, E, msk, cur_f, cur_b, colv);

    // ---- out[0] = r0 ; xb = bf16(dc .* r0) ----
    init_kernel<<<2048, THREADS, 0, stream>>>(r0, out, dc, xb, (int)(ND / 4));

    // ---- 5 steps of degree-2 Taylor: r+ = r + g1*Lr + g2*L^2 r ----
    const float g[2] = {DT_C, DT_C * DT_C / 2.f};
    int gridR = (N + 3) / 4;

    for (int s = 0; s < 5; ++s) {
        const float* r  = out + (size_t)s * ND;
        float*       rn = out + (size_t)(s + 1) * ND;
        for (int st = 0; st < 2; ++st) {
            spmm_h1<<<gridR, THREADS, 0, stream>>>(row_ptr, cur_f, colv, s1, xb, t1b, N);
            if (st == 0)
                spmm_h2<0><<<gridR, THREADS, 0, stream>>>(row_ptr, colv, dr, dc, s1, msk, t1b, r, rn, xb, g[st], N);
            else
                spmm_h2<3><<<gridR, THREADS, 0, stream>>>(row_ptr, colv, dr, dc, s1, msk, t1b, r, rn, xb, g[st], N);
        }
    }
}

// Round 12
// 1099.925 us; speedup vs baseline: 1.0818x; 1.0008x over previous
//
#include <hip/hip_runtime.h>

#define THREADS 256
#define SCAN_CHUNK 2048
#define DT_C 0.2f

__device__ __forceinline__ unsigned pack_bf16(float x, float y) {
    unsigned xb = __float_as_uint(x);
    unsigned yb = __float_as_uint(y);
    xb = (xb + 0x7fffu + ((xb >> 16) & 1u)) >> 16;
    yb = (yb + 0x7fffu + ((yb >> 16) & 1u)) >> 16;
    return xb | (yb << 16);
}
__device__ __forceinline__ float lo16(unsigned u) { return __uint_as_float(u << 16); }
__device__ __forceinline__ float hi16(unsigned u) { return __uint_as_float(u & 0xffff0000u); }

// ---------------- CSR build ----------------

__global__ void count_deg_kernel(const int* __restrict__ ei, int E,
                                 int* __restrict__ deg_r, int* __restrict__ deg_c) {
    int e = blockIdx.x * blockDim.x + threadIdx.x;
    if (e < E) {
        atomicAdd(&deg_r[ei[e]], 1);
        atomicAdd(&deg_c[ei[e + E]], 1);
    }
}

__global__ void scan_phase1(const int* __restrict__ deg, int n, int* __restrict__ bsums) {
    int base = blockIdx.x * SCAN_CHUNK;
    int sum = 0;
    for (int i = threadIdx.x; i < SCAN_CHUNK; i += THREADS) {
        int idx = base + i;
        if (idx < n) sum += deg[idx];
    }
    __shared__ int wsum[4];
    int lane = threadIdx.x & 63, wid = threadIdx.x >> 6;
    for (int off = 32; off; off >>= 1) sum += __shfl_down(sum, off);
    if (lane == 0) wsum[wid] = sum;
    __syncthreads();
    if (threadIdx.x == 0)
        bsums[blockIdx.x] = wsum[0] + wsum[1] + wsum[2] + wsum[3];
}

__global__ void scan_phase2(int* __restrict__ bsums, int nb,
                            int* __restrict__ row_ptr, int N, int E) {
    if (blockIdx.x == 0 && threadIdx.x == 0) {
        int acc = 0;
        for (int b = 0; b < nb; ++b) { int v = bsums[b]; bsums[b] = acc; acc += v; }
        row_ptr[N] = E;
    }
}

__global__ void scan_phase3(const int* __restrict__ deg, int n, const int* __restrict__ bsums,
                            int* __restrict__ row_ptr, int* __restrict__ cur_f,
                            int* __restrict__ cur_b) {
    int base = blockIdx.x * SCAN_CHUNK;
    int tbase = base + threadIdx.x * 8;
    int my[8]; int s = 0;
#pragma unroll
    for (int j = 0; j < 8; ++j) { int idx = tbase + j; my[j] = (idx < n) ? deg[idx] : 0; s += my[j]; }
    int lane = threadIdx.x & 63, wid = threadIdx.x >> 6;
    int v = s;
    for (int off = 1; off < 64; off <<= 1) { int t = __shfl_up(v, off); if (lane >= off) v += t; }
    __shared__ int wsum[4];
    if (lane == 63) wsum[wid] = v;
    __syncthreads();
    int woff = 0;
    for (int w = 0; w < wid; ++w) woff += wsum[w];
    int acc = bsums[blockIdx.x] + woff + (v - s);
#pragma unroll
    for (int j = 0; j < 8; ++j) {
        int idx = tbase + j;
        if (idx < n) { row_ptr[idx] = acc; cur_f[idx] = acc; cur_b[idx] = acc + my[j]; }
        acc += my[j];
    }
}

// dr = deg_r^-1/2, dc = deg_c^-1/2, s1 = dr*dc
__global__ void make_dinv(const int* __restrict__ deg_r, const int* __restrict__ deg_c,
                          float* __restrict__ dr, float* __restrict__ dc,
                          float* __restrict__ s1, int n) {
    int i = blockIdx.x * blockDim.x + threadIdx.x;
    if (i < n) {
        int ra = deg_r[i];
        float a = ra > 0 ? rsqrtf((float)ra) : 0.f;
        int cb = deg_c[i];
        float b = cb > 0 ? rsqrtf((float)cb) : 0.f;
        dr[i] = a; dc[i] = b; s1[i] = a * b;
    }
}

// Partitioned scatter: masked edges from the row front, unmasked from the back.
// cur_f[r] ends as the split point.
__global__ void build_csr_kernel(const int* __restrict__ ei, int E,
                                 const int* __restrict__ mask,
                                 int* __restrict__ cur_f, int* __restrict__ cur_b,
                                 int* __restrict__ colv) {
    int e = blockIdx.x * blockDim.x + threadIdx.x;
    if (e < E) {
        int r = ei[e], c = ei[e + E];
        int p;
        if (mask[c]) p = atomicAdd(&cur_f[r], 1);
        else         p = atomicSub(&cur_b[r], 1) - 1;
        colv[p] = c;
    }
}

// ---------------- init: out[0] = r0 ; xb = bf16(dc .* r0) ----------------

__global__ void init_kernel(const float* __restrict__ r0, float* __restrict__ out0,
                            const float* __restrict__ dc,
                            unsigned* __restrict__ xb, int n4) {
    int i = blockIdx.x * blockDim.x + threadIdx.x;
    int stride = gridDim.x * blockDim.x;
    const float4* r4 = (const float4*)r0;
    float4* o4 = (float4*)out0;
    for (; i < n4; i += stride) {
        float4 a = r4[i];
        o4[i] = a;
        float w = dc[i >> 4];   // 16 float4s per node
        xb[2 * i]     = pack_bf16(w * a.x, w * a.y);
        xb[2 * i + 1] = pack_bf16(w * a.z, w * a.w);
    }
}

// ---------------- SpMM hop 1 ----------------
// Quarter-wave per edge, uint2 (8B) per lane: one VMEM instr = 4 edges (512B).
// Cascade 16/8/1 per quarter-wave (4/2/1 loads). Gathers bf16(dc .* x) over the
// masked front segment; pure gather-add. t1b = bf16(s1[row] * sum).

__global__ __launch_bounds__(256) void spmm_h1(const int* __restrict__ row_ptr,
                                               const int* __restrict__ split,
                                               const int* __restrict__ cols,
                                               const float* __restrict__ s1,
                                               const unsigned* __restrict__ xb,
                                               unsigned* __restrict__ t1b, int n) {
    int row = blockIdx.x * 4 + (threadIdx.x >> 6);
    if (row >= n) return;
    int l = threadIdx.x & 63, q = l >> 4, ql = l & 15;
    int s = row_ptr[row], e = split[row];
    const uint2* x2 = (const uint2*)xb;
    float a0 = 0.f, a1 = 0.f, a2 = 0.f, a3 = 0.f;
    int j = s + q;
    for (; j + 12 < e; j += 16) {              // 4 loads per quarter-wave
        int c0 = cols[j], c1 = cols[j + 4], c2 = cols[j + 8], c3 = cols[j + 12];
        uint2 u0 = x2[(size_t)c0 * 16 + ql], u1 = x2[(size_t)c1 * 16 + ql];
        uint2 u2 = x2[(size_t)c2 * 16 + ql], u3 = x2[(size_t)c3 * 16 + ql];
        a0 += lo16(u0.x) + lo16(u1.x);  a1 += hi16(u0.x) + hi16(u1.x);
        a2 += lo16(u0.y) + lo16(u1.y);  a3 += hi16(u0.y) + hi16(u1.y);
        a0 += lo16(u2.x) + lo16(u3.x);  a1 += hi16(u2.x) + hi16(u3.x);
        a2 += lo16(u2.y) + lo16(u3.y);  a3 += hi16(u2.y) + hi16(u3.y);
    }
    for (; j + 4 < e; j += 8) {                // 2 loads
        int c0 = cols[j], c1 = cols[j + 4];
        uint2 u0 = x2[(size_t)c0 * 16 + ql], u1 = x2[(size_t)c1 * 16 + ql];
        a0 += lo16(u0.x) + lo16(u1.x);  a1 += hi16(u0.x) + hi16(u1.x);
        a2 += lo16(u0.y) + lo16(u1.y);  a3 += hi16(u0.y) + hi16(u1.y);
    }
    for (; j < e; j += 4) {                    // 1 load
        uint2 u0 = x2[(size_t)cols[j] * 16 + ql];
        a0 += lo16(u0.x);  a1 += hi16(u0.x);
        a2 += lo16(u0.y);  a3 += hi16(u0.y);
    }
    a0 += __shfl_xor(a0, 16);  a1 += __shfl_xor(a1, 16);
    a2 += __shfl_xor(a2, 16);  a3 += __shfl_xor(a3, 16);
    a0 += __shfl_xor(a0, 32);  a1 += __shfl_xor(a1, 32);
    a2 += __shfl_xor(a2, 32);  a3 += __shfl_xor(a3, 32);
    if (l < 16) {
        float w = s1[row];
        ((uint2*)t1b)[(size_t)row * 16 + ql] =
            make_uint2(pack_bf16(w * a0, w * a1), pack_bf16(w * a2, w * a3));
    }
}

// ---------------- SpMM hop 2 + fused Taylor epilogue ----------------
// a = sum t1b[col] over the FULL segment (dc pre-folded into t1b); k = -dr*a.
// ST==0 (first): rn = r + g*k ; xb = bf16(dc*k) = bf16(-s1*a)  [masked rows only]
// ST==3 (last):  rn += g*k    ; xb = bf16(dc*rn)               [masked rows only]

template <int ST>
__global__ __launch_bounds__(256) void spmm_h2(const int* __restrict__ row_ptr,
                                               const int* __restrict__ cols,
                                               const float* __restrict__ dr_arr,
                                               const float* __restrict__ dc_arr,
                                               const float* __restrict__ s1,
                                               const int* __restrict__ msk,
                                               const unsigned* __restrict__ t1b,
                                               const float* __restrict__ r_prev,
                                               float* __restrict__ rn,
                                               unsigned* __restrict__ xb,
                                               float g, int n) {
    int row = blockIdx.x * 4 + (threadIdx.x >> 6);
    if (row >= n) return;
    int l = threadIdx.x & 63, q = l >> 4, ql = l & 15;
    int s = row_ptr[row], e = row_ptr[row + 1];
    const uint2* t2 = (const uint2*)t1b;
    float a0 = 0.f, a1 = 0.f, a2 = 0.f, a3 = 0.f;
    int j = s + q;
    for (; j + 12 < e; j += 16) {
        int c0 = cols[j], c1 = cols[j + 4], c2 = cols[j + 8], c3 = cols[j + 12];
        uint2 u0 = t2[(size_t)c0 * 16 + ql], u1 = t2[(size_t)c1 * 16 + ql];
        uint2 u2 = t2[(size_t)c2 * 16 + ql], u3 = t2[(size_t)c3 * 16 + ql];
        a0 += lo16(u0.x) + lo16(u1.x);  a1 += hi16(u0.x) + hi16(u1.x);
        a2 += lo16(u0.y) + lo16(u1.y);  a3 += hi16(u0.y) + hi16(u1.y);
        a0 += lo16(u2.x) + lo16(u3.x);  a1 += hi16(u2.x) + hi16(u3.x);
        a2 += lo16(u2.y) + lo16(u3.y);  a3 += hi16(u2.y) + hi16(u3.y);
    }
    for (; j + 4 < e; j += 8) {
        int c0 = cols[j], c1 = cols[j + 4];
        uint2 u0 = t2[(size_t)c0 * 16 + ql], u1 = t2[(size_t)c1 * 16 + ql];
        a0 += lo16(u0.x) + lo16(u1.x);  a1 += hi16(u0.x) + hi16(u1.x);
        a2 += lo16(u0.y) + lo16(u1.y);  a3 += hi16(u0.y) + hi16(u1.y);
    }
    for (; j < e; j += 4) {
        uint2 u0 = t2[(size_t)cols[j] * 16 + ql];
        a0 += lo16(u0.x);  a1 += hi16(u0.x);
        a2 += lo16(u0.y);  a3 += hi16(u0.y);
    }
    a0 += __shfl_xor(a0, 16);  a1 += __shfl_xor(a1, 16);
    a2 += __shfl_xor(a2, 16);  a3 += __shfl_xor(a3, 16);
    a0 += __shfl_xor(a0, 32);  a1 += __shfl_xor(a1, 32);
    a2 += __shfl_xor(a2, 32);  a3 += __shfl_xor(a3, 32);
    if (l < 16) {
        float dr_ = dr_arr[row];
        float k0 = -dr_ * a0, k1 = -dr_ * a1, k2 = -dr_ * a2, k3 = -dr_ * a3;
        size_t idx = (size_t)row * 16 + ql;
        const float4* r4p = (const float4*)r_prev;
        float4* rn4 = (float4*)rn;
        uint2* x2w = (uint2*)xb;
        bool m = msk[row] != 0;   // xb only ever gathered for masked rows
        if (ST == 0) {
            float4 rv = r4p[idx];
            rn4[idx] = make_float4(rv.x + g * k0, rv.y + g * k1,
                                   rv.z + g * k2, rv.w + g * k3);
            if (m) {
                float w = s1[row];
                x2w[idx] = make_uint2(pack_bf16(-w * a0, -w * a1),
                                      pack_bf16(-w * a2, -w * a3));   // dc*k
            }
        } else {
            float4 p = rn4[idx];
            p.x += g * k0; p.y += g * k1; p.z += g * k2; p.w += g * k3;
            rn4[idx] = p;
            if (m) {
                float dc_ = dc_arr[row];
                x2w[idx] = make_uint2(pack_bf16(dc_ * p.x, dc_ * p.y),
                                      pack_bf16(dc_ * p.z, dc_ * p.w));
            }
        }
    }
}

// ---------------- host ----------------

extern "C" void kernel_launch(void* const* d_in, const int* in_sizes, int n_in,
                              void* d_out, int out_size, void* d_ws, size_t ws_size,
                              hipStream_t stream) {
    const float* r0  = (const float*)d_in[0];
    const int*   ei  = (const int*)d_in[1];
    const int*   msk = (const int*)d_in[2];
    float* out = (float*)d_out;

    const int N = in_sizes[2];
    const int E = in_sizes[1] / 2;
    const size_t ND = (size_t)N * 64;

    char* ws = (char*)d_ws;
    size_t off = 0;
    auto carve = [&](size_t bytes) -> void* {
        off = (off + 255) & ~(size_t)255;
        void* p = ws + off;
        off += bytes;
        return p;
    };
    int*      deg_r   = (int*)carve((size_t)N * 4);
    int*      deg_c   = (int*)carve((size_t)N * 4);
    int*      row_ptr = (int*)carve((size_t)(N + 1) * 4);
    int*      cur_f   = (int*)carve((size_t)N * 4);   // front cursor -> split point
    int*      cur_b   = (int*)carve((size_t)N * 4);   // back cursor
    int*      bsums   = (int*)carve(1024 * 4);
    float*    dr      = (float*)carve((size_t)N * 4);
    float*    dc      = (float*)carve((size_t)N * 4);
    float*    s1      = (float*)carve((size_t)N * 4);
    int*      colv    = (int*)carve((size_t)E * 4);
    unsigned* xb      = (unsigned*)carve((size_t)N * 32 * 4);
    unsigned* t1b     = (unsigned*)carve((size_t)N * 32 * 4);

    // ---- CSR build (edges partitioned [masked | unmasked] within each row) ----
    hipMemsetAsync(deg_r, 0, (size_t)N * 4, stream);
    hipMemsetAsync(deg_c, 0, (size_t)N * 4, stream);
    int gE = (E + THREADS - 1) / THREADS;
    count_deg_kernel<<<gE, THREADS, 0, stream>>>(ei, E, deg_r, deg_c);
    int nb = (N + SCAN_CHUNK - 1) / SCAN_CHUNK;
    scan_phase1<<<nb, THREADS, 0, stream>>>(deg_r, N, bsums);
    scan_phase2<<<1, 64, 0, stream>>>(bsums, nb, row_ptr, N, E);
    scan_phase3<<<nb, THREADS, 0, stream>>>(deg_r, N, bsums, row_ptr, cur_f, cur_b);
    make_dinv<<<(N + THREADS - 1) / THREADS, THREADS, 0, stream>>>(deg_r, deg_c, dr, dc, s1, N);
    build_csr_kernel<<<gE, THREADS, 0, stream>>>(ei, E, msk, cur_f, cur_b, colv);

    // ---- out[0] = r0 ; xb = bf16(dc .* r0) ----
    init_kernel<<<2048, THREADS, 0, stream>>>(r0, out, dc, xb, (int)(ND / 4));

    // ---- 5 steps of degree-2 Taylor: r+ = r + g1*Lr + g2*L^2 r ----
    const float g[2] = {DT_C, DT_C * DT_C / 2.f};
    int gridR = (N + 3) / 4;

    for (int s = 0; s < 5; ++s) {
        const float* r  = out + (size_t)s * ND;
        float*       rn = out + (size_t)(s + 1) * ND;
        for (int st = 0; st < 2; ++st) {
            spmm_h1<<<gridR, THREADS, 0, stream>>>(row_ptr, cur_f, colv, s1, xb, t1b, N);
            if (st == 0)
                spmm_h2<0><<<gridR, THREADS, 0, stream>>>(row_ptr, colv, dr, dc, s1, msk, t1b, r, rn, xb, g[st], N);
            else
                spmm_h2<3><<<gridR, THREADS, 0, stream>>>(row_ptr, colv, dr, dc, s1, msk, t1b, r, rn, xb, g[st], N);
        }
    }
}

// Round 13
// 910.970 us; speedup vs baseline: 1.3062x; 1.2074x over previous
//
#include <hip/hip_runtime.h>

#define THREADS 256
#define SCAN_CHUNK 2048
#define DT_C 0.2f

__device__ __forceinline__ unsigned pack_bf16(float x, float y) {
    unsigned xb = __float_as_uint(x);
    unsigned yb = __float_as_uint(y);
    xb = (xb + 0x7fffu + ((xb >> 16) & 1u)) >> 16;
    yb = (yb + 0x7fffu + ((yb >> 16) & 1u)) >> 16;
    return xb | (yb << 16);
}
__device__ __forceinline__ float lo16(unsigned u) { return __uint_as_float(u << 16); }
__device__ __forceinline__ float hi16(unsigned u) { return __uint_as_float(u & 0xffff0000u); }

// ---------------- CSR build ----------------

__global__ void count_deg_kernel(const int* __restrict__ ei, int E,
                                 int* __restrict__ deg_r, int* __restrict__ deg_c) {
    int e = blockIdx.x * blockDim.x + threadIdx.x;
    if (e < E) {
        atomicAdd(&deg_r[ei[e]], 1);
        atomicAdd(&deg_c[ei[e + E]], 1);
    }
}

__global__ void scan_phase1(const int* __restrict__ deg, int n, int* __restrict__ bsums) {
    int base = blockIdx.x * SCAN_CHUNK;
    int sum = 0;
    for (int i = threadIdx.x; i < SCAN_CHUNK; i += THREADS) {
        int idx = base + i;
        if (idx < n) sum += deg[idx];
    }
    __shared__ int wsum[4];
    int lane = threadIdx.x & 63, wid = threadIdx.x >> 6;
    for (int off = 32; off; off >>= 1) sum += __shfl_down(sum, off);
    if (lane == 0) wsum[wid] = sum;
    __syncthreads();
    if (threadIdx.x == 0)
        bsums[blockIdx.x] = wsum[0] + wsum[1] + wsum[2] + wsum[3];
}

__global__ void scan_phase2(int* __restrict__ bsums, int nb,
                            int* __restrict__ row_ptr, int N, int E) {
    if (blockIdx.x == 0 && threadIdx.x == 0) {
        int acc = 0;
        for (int b = 0; b < nb; ++b) { int v = bsums[b]; bsums[b] = acc; acc += v; }
        row_ptr[N] = E;
    }
}

__global__ void scan_phase3(const int* __restrict__ deg, int n, const int* __restrict__ bsums,
                            int* __restrict__ row_ptr, int* __restrict__ cur_f,
                            int* __restrict__ cur_b) {
    int base = blockIdx.x * SCAN_CHUNK;
    int tbase = base + threadIdx.x * 8;
    int my[8]; int s = 0;
#pragma unroll
    for (int j = 0; j < 8; ++j) { int idx = tbase + j; my[j] = (idx < n) ? deg[idx] : 0; s += my[j]; }
    int lane = threadIdx.x & 63, wid = threadIdx.x >> 6;
    int v = s;
    for (int off = 1; off < 64; off <<= 1) { int t = __shfl_up(v, off); if (lane >= off) v += t; }
    __shared__ int wsum[4];
    if (lane == 63) wsum[wid] = v;
    __syncthreads();
    int woff = 0;
    for (int w = 0; w < wid; ++w) woff += wsum[w];
    int acc = bsums[blockIdx.x] + woff + (v - s);
#pragma unroll
    for (int j = 0; j < 8; ++j) {
        int idx = tbase + j;
        if (idx < n) { row_ptr[idx] = acc; cur_f[idx] = acc; cur_b[idx] = acc + my[j]; }
        acc += my[j];
    }
}

// dr = deg_r^-1/2, dc = deg_c^-1/2, s1 = dr*dc
__global__ void make_dinv(const int* __restrict__ deg_r, const int* __restrict__ deg_c,
                          float* __restrict__ dr, float* __restrict__ dc,
                          float* __restrict__ s1, int n) {
    int i = blockIdx.x * blockDim.x + threadIdx.x;
    if (i < n) {
        int ra = deg_r[i];
        float a = ra > 0 ? rsqrtf((float)ra) : 0.f;
        int cb = deg_c[i];
        float b = cb > 0 ? rsqrtf((float)cb) : 0.f;
        dr[i] = a; dc[i] = b; s1[i] = a * b;
    }
}

// Partitioned scatter: masked edges from the row front, unmasked from the back.
// cur_f[r] ends as the split point.
__global__ void build_csr_kernel(const int* __restrict__ ei, int E,
                                 const int* __restrict__ mask,
                                 int* __restrict__ cur_f, int* __restrict__ cur_b,
                                 int* __restrict__ colv) {
    int e = blockIdx.x * blockDim.x + threadIdx.x;
    if (e < E) {
        int r = ei[e], c = ei[e + E];
        int p;
        if (mask[c]) p = atomicAdd(&cur_f[r], 1);
        else         p = atomicSub(&cur_b[r], 1) - 1;
        colv[p] = c;
    }
}

// ---------------- init: out[0] = r0 ; xb = bf16(dc .* r0) ----------------

__global__ void init_kernel(const float* __restrict__ r0, float* __restrict__ out0,
                            const float* __restrict__ dc,
                            unsigned* __restrict__ xb, int n4) {
    int i = blockIdx.x * blockDim.x + threadIdx.x;
    int stride = gridDim.x * blockDim.x;
    const float4* r4 = (const float4*)r0;
    float4* o4 = (float4*)out0;
    for (; i < n4; i += stride) {
        float4 a = r4[i];
        o4[i] = a;
        float w = dc[i >> 4];   // 16 float4s per node
        xb[2 * i]     = pack_bf16(w * a.x, w * a.y);
        xb[2 * i + 1] = pack_bf16(w * a.z, w * a.w);
    }
}

// ---------------- SpMM hop 1 ----------------
// TWO rows per wave (one per 32-lane half). Within a half: 2 edge-slots x
// 16 lanes x uint2 (8B) = 2 edges per VMEM instr. Level cascade per row is
// the proven 16/8/4/1 (8/4/2/1 loads per slot); the wave keeps up to 16
// independent VMEM batches (4KB, 64 lines) in flight = 2x round 12.
// Gathers bf16(dc .* x) over the masked front segment; t1b = bf16(s1*sum).

__global__ __launch_bounds__(256) void spmm_h1(const int* __restrict__ row_ptr,
                                               const int* __restrict__ split,
                                               const int* __restrict__ cols,
                                               const float* __restrict__ s1,
                                               const unsigned* __restrict__ xb,
                                               unsigned* __restrict__ t1b, int n) {
    int l = threadIdx.x & 63;
    int h = l >> 5, hq = (l >> 4) & 1, ql = l & 15;
    int row = blockIdx.x * 8 + (threadIdx.x >> 6) * 2 + h;
    if (row >= n) return;
    int s = row_ptr[row], e = split[row];
    const uint2* x2 = (const uint2*)xb;
    float a0 = 0.f, a1 = 0.f, a2 = 0.f, a3 = 0.f;
    int j = s + hq;
    for (; j + 14 < e; j += 16) {              // 16-edge level: 8 loads/slot
        int c0 = cols[j],      c1 = cols[j + 2],  c2 = cols[j + 4],  c3 = cols[j + 6];
        int c4 = cols[j + 8],  c5 = cols[j + 10], c6 = cols[j + 12], c7 = cols[j + 14];
        uint2 u0 = x2[(size_t)c0 * 16 + ql], u1 = x2[(size_t)c1 * 16 + ql];
        uint2 u2 = x2[(size_t)c2 * 16 + ql], u3 = x2[(size_t)c3 * 16 + ql];
        uint2 u4 = x2[(size_t)c4 * 16 + ql], u5 = x2[(size_t)c5 * 16 + ql];
        uint2 u6 = x2[(size_t)c6 * 16 + ql], u7 = x2[(size_t)c7 * 16 + ql];
        a0 += lo16(u0.x) + lo16(u1.x);  a1 += hi16(u0.x) + hi16(u1.x);
        a2 += lo16(u0.y) + lo16(u1.y);  a3 += hi16(u0.y) + hi16(u1.y);
        a0 += lo16(u2.x) + lo16(u3.x);  a1 += hi16(u2.x) + hi16(u3.x);
        a2 += lo16(u2.y) + lo16(u3.y);  a3 += hi16(u2.y) + hi16(u3.y);
        a0 += lo16(u4.x) + lo16(u5.x);  a1 += hi16(u4.x) + hi16(u5.x);
        a2 += lo16(u4.y) + lo16(u5.y);  a3 += hi16(u4.y) + hi16(u5.y);
        a0 += lo16(u6.x) + lo16(u7.x);  a1 += hi16(u6.x) + hi16(u7.x);
        a2 += lo16(u6.y) + lo16(u7.y);  a3 += hi16(u6.y) + hi16(u7.y);
    }
    for (; j + 6 < e; j += 8) {                // 8-edge level: 4 loads/slot
        int c0 = cols[j], c1 = cols[j + 2], c2 = cols[j + 4], c3 = cols[j + 6];
        uint2 u0 = x2[(size_t)c0 * 16 + ql], u1 = x2[(size_t)c1 * 16 + ql];
        uint2 u2 = x2[(size_t)c2 * 16 + ql], u3 = x2[(size_t)c3 * 16 + ql];
        a0 += lo16(u0.x) + lo16(u1.x);  a1 += hi16(u0.x) + hi16(u1.x);
        a2 += lo16(u0.y) + lo16(u1.y);  a3 += hi16(u0.y) + hi16(u1.y);
        a0 += lo16(u2.x) + lo16(u3.x);  a1 += hi16(u2.x) + hi16(u3.x);
        a2 += lo16(u2.y) + lo16(u3.y);  a3 += hi16(u2.y) + hi16(u3.y);
    }
    for (; j + 2 < e; j += 4) {                // 4-edge level: 2 loads/slot
        int c0 = cols[j], c1 = cols[j + 2];
        uint2 u0 = x2[(size_t)c0 * 16 + ql], u1 = x2[(size_t)c1 * 16 + ql];
        a0 += lo16(u0.x) + lo16(u1.x);  a1 += hi16(u0.x) + hi16(u1.x);
        a2 += lo16(u0.y) + lo16(u1.y);  a3 += hi16(u0.y) + hi16(u1.y);
    }
    for (; j < e; j += 2) {                    // final: 1 load/slot (<=1 iter)
        uint2 u0 = x2[(size_t)cols[j] * 16 + ql];
        a0 += lo16(u0.x);  a1 += hi16(u0.x);
        a2 += lo16(u0.y);  a3 += hi16(u0.y);
    }
    a0 += __shfl_xor(a0, 16);  a1 += __shfl_xor(a1, 16);
    a2 += __shfl_xor(a2, 16);  a3 += __shfl_xor(a3, 16);
    if ((l & 31) < 16) {
        float w = s1[row];
        ((uint2*)t1b)[(size_t)row * 16 + ql] =
            make_uint2(pack_bf16(w * a0, w * a1), pack_bf16(w * a2, w * a3));
    }
}

// ---------------- SpMM hop 2 + fused Taylor epilogue ----------------
// Two rows per wave, same engine over the FULL segment; k = -dr*a.
// ST==0 (first): rn = r + g*k ; xb = bf16(dc*k) = bf16(-s1*a)  [masked rows only]
// ST==3 (last):  rn += g*k    ; xb = bf16(dc*rn)               [masked rows only]

template <int ST>
__global__ __launch_bounds__(256) void spmm_h2(const int* __restrict__ row_ptr,
                                               const int* __restrict__ cols,
                                               const float* __restrict__ dr_arr,
                                               const float* __restrict__ dc_arr,
                                               const float* __restrict__ s1,
                                               const int* __restrict__ msk,
                                               const unsigned* __restrict__ t1b,
                                               const float* __restrict__ r_prev,
                                               float* __restrict__ rn,
                                               unsigned* __restrict__ xb,
                                               float g, int n) {
    int l = threadIdx.x & 63;
    int h = l >> 5, hq = (l >> 4) & 1, ql = l & 15;
    int row = blockIdx.x * 8 + (threadIdx.x >> 6) * 2 + h;
    if (row >= n) return;
    int s = row_ptr[row], e = row_ptr[row + 1];
    const uint2* t2 = (const uint2*)t1b;
    float a0 = 0.f, a1 = 0.f, a2 = 0.f, a3 = 0.f;
    int j = s + hq;
    for (; j + 14 < e; j += 16) {
        int c0 = cols[j],      c1 = cols[j + 2],  c2 = cols[j + 4],  c3 = cols[j + 6];
        int c4 = cols[j + 8],  c5 = cols[j + 10], c6 = cols[j + 12], c7 = cols[j + 14];
        uint2 u0 = t2[(size_t)c0 * 16 + ql], u1 = t2[(size_t)c1 * 16 + ql];
        uint2 u2 = t2[(size_t)c2 * 16 + ql], u3 = t2[(size_t)c3 * 16 + ql];
        uint2 u4 = t2[(size_t)c4 * 16 + ql], u5 = t2[(size_t)c5 * 16 + ql];
        uint2 u6 = t2[(size_t)c6 * 16 + ql], u7 = t2[(size_t)c7 * 16 + ql];
        a0 += lo16(u0.x) + lo16(u1.x);  a1 += hi16(u0.x) + hi16(u1.x);
        a2 += lo16(u0.y) + lo16(u1.y);  a3 += hi16(u0.y) + hi16(u1.y);
        a0 += lo16(u2.x) + lo16(u3.x);  a1 += hi16(u2.x) + hi16(u3.x);
        a2 += lo16(u2.y) + lo16(u3.y);  a3 += hi16(u2.y) + hi16(u3.y);
        a0 += lo16(u4.x) + lo16(u5.x);  a1 += hi16(u4.x) + hi16(u5.x);
        a2 += lo16(u4.y) + lo16(u5.y);  a3 += hi16(u4.y) + hi16(u5.y);
        a0 += lo16(u6.x) + lo16(u7.x);  a1 += hi16(u6.x) + hi16(u7.x);
        a2 += lo16(u6.y) + lo16(u7.y);  a3 += hi16(u6.y) + hi16(u7.y);
    }
    for (; j + 6 < e; j += 8) {
        int c0 = cols[j], c1 = cols[j + 2], c2 = cols[j + 4], c3 = cols[j + 6];
        uint2 u0 = t2[(size_t)c0 * 16 + ql], u1 = t2[(size_t)c1 * 16 + ql];
        uint2 u2 = t2[(size_t)c2 * 16 + ql], u3 = t2[(size_t)c3 * 16 + ql];
        a0 += lo16(u0.x) + lo16(u1.x);  a1 += hi16(u0.x) + hi16(u1.x);
        a2 += lo16(u0.y) + lo16(u1.y);  a3 += hi16(u0.y) + hi16(u1.y);
        a0 += lo16(u2.x) + lo16(u3.x);  a1 += hi16(u2.x) + hi16(u3.x);
        a2 += lo16(u2.y) + lo16(u3.y);  a3 += hi16(u2.y) + hi16(u3.y);
    }
    for (; j + 2 < e; j += 4) {
        int c0 = cols[j], c1 = cols[j + 2];
        uint2 u0 = t2[(size_t)c0 * 16 + ql], u1 = t2[(size_t)c1 * 16 + ql];
        a0 += lo16(u0.x) + lo16(u1.x);  a1 += hi16(u0.x) + hi16(u1.x);
        a2 += lo16(u0.y) + lo16(u1.y);  a3 += hi16(u0.y) + hi16(u1.y);
    }
    for (; j < e; j += 2) {
        uint2 u0 = t2[(size_t)cols[j] * 16 + ql];
        a0 += lo16(u0.x);  a1 += hi16(u0.x);
        a2 += lo16(u0.y);  a3 += hi16(u0.y);
    }
    a0 += __shfl_xor(a0, 16);  a1 += __shfl_xor(a1, 16);
    a2 += __shfl_xor(a2, 16);  a3 += __shfl_xor(a3, 16);
    if ((l & 31) < 16) {
        float dr_ = dr_arr[row];
        float k0 = -dr_ * a0, k1 = -dr_ * a1, k2 = -dr_ * a2, k3 = -dr_ * a3;
        size_t idx = (size_t)row * 16 + ql;
        const float4* r4p = (const float4*)r_prev;
        float4* rn4 = (float4*)rn;
        uint2* x2w = (uint2*)xb;
        bool m = msk[row] != 0;   // xb only ever gathered for masked rows
        if (ST == 0) {
            float4 rv = r4p[idx];
            rn4[idx] = make_float4(rv.x + g * k0, rv.y + g * k1,
                                   rv.z + g * k2, rv.w + g * k3);
            if (m) {
                float w = s1[row];
                x2w[idx] = make_uint2(pack_bf16(-w * a0, -w * a1),
                                      pack_bf16(-w * a2, -w * a3));   // dc*k
            }
        } else {
            float4 p = rn4[idx];
            p.x += g * k0; p.y += g * k1; p.z += g * k2; p.w += g * k3;
            rn4[idx] = p;
            if (m) {
                float dc_ = dc_arr[row];
                x2w[idx] = make_uint2(pack_bf16(dc_ * p.x, dc_ * p.y),
                                      pack_bf16(dc_ * p.z, dc_ * p.w));
            }
        }
    }
}

// ---------------- host ----------------

extern "C" void kernel_launch(void* const* d_in, const int* in_sizes, int n_in,
                              void* d_out, int out_size, void* d_ws, size_t ws_size,
                              hipStream_t stream) {
    const float* r0  = (const float*)d_in[0];
    const int*   ei  = (const int*)d_in[1];
    const int*   msk = (const int*)d_in[2];
    float* out = (float*)d_out;

    const int N = in_sizes[2];
    const int E = in_sizes[1] / 2;
    const size_t ND = (size_t)N * 64;

    char* ws = (char*)d_ws;
    size_t off = 0;
    auto carve = [&](size_t bytes) -> void* {
        off = (off + 255) & ~(size_t)255;
        void* p = ws + off;
        off += bytes;
        return p;
    };
    int*      deg_r   = (int*)carve((size_t)N * 4);
    int*      deg_c   = (int*)carve((size_t)N * 4);
    int*      row_ptr = (int*)carve((size_t)(N + 1) * 4);
    int*      cur_f   = (int*)carve((size_t)N * 4);   // front cursor -> split point
    int*      cur_b   = (int*)carve((size_t)N * 4);   // back cursor
    int*      bsums   = (int*)carve(1024 * 4);
    float*    dr      = (float*)carve((size_t)N * 4);
    float*    dc      = (float*)carve((size_t)N * 4);
    float*    s1      = (float*)carve((size_t)N * 4);
    int*      colv    = (int*)carve((size_t)E * 4);
    unsigned* xb      = (unsigned*)carve((size_t)N * 32 * 4);
    unsigned* t1b     = (unsigned*)carve((size_t)N * 32 * 4);

    // ---- CSR build (edges partitioned [masked | unmasked] within each row) ----
    hipMemsetAsync(deg_r, 0, (size_t)N * 4, stream);
    hipMemsetAsync(deg_c, 0, (size_t)N * 4, stream);
    int gE = (E + THREADS - 1) / THREADS;
    count_deg_kernel<<<gE, THREADS, 0, stream>>>(ei, E, deg_r, deg_c);
    int nb = (N + SCAN_CHUNK - 1) / SCAN_CHUNK;
    scan_phase1<<<nb, THREADS, 0, stream>>>(deg_r, N, bsums);
    scan_phase2<<<1, 64, 0, stream>>>(bsums, nb, row_ptr, N, E);
    scan_phase3<<<nb, THREADS, 0, stream>>>(deg_r, N, bsums, row_ptr, cur_f, cur_b);
    make_dinv<<<(N + THREADS - 1) / THREADS, THREADS, 0, stream>>>(deg_r, deg_c, dr, dc, s1, N);
    build_csr_kernel<<<gE, THREADS, 0, stream>>>(ei, E, msk, cur_f, cur_b, colv);

    // ---- out[0] = r0 ; xb = bf16(dc .* r0) ----
    init_kernel<<<2048, THREADS, 0, stream>>>(r0, out, dc, xb, (int)(ND / 4));

    // ---- 5 steps of degree-2 Taylor: r+ = r + g1*Lr + g2*L^2 r ----
    const float g[2] = {DT_C, DT_C * DT_C / 2.f};
    int gridR = (N + 7) / 8;

    for (int s = 0; s < 5; ++s) {
        const float* r  = out + (size_t)s * ND;
        float*       rn = out + (size_t)(s + 1) * ND;
        for (int st = 0; st < 2; ++st) {
            spmm_h1<<<gridR, THREADS, 0, stream>>>(row_ptr, cur_f, colv, s1, xb, t1b, N);
            if (st == 0)
                spmm_h2<0><<<gridR, THREADS, 0, stream>>>(row_ptr, colv, dr, dc, s1, msk, t1b, r, rn, xb, g[st], N);
            else
                spmm_h2<3><<<gridR, THREADS, 0, stream>>>(row_ptr, colv, dr, dc, s1, msk, t1b, r, rn, xb, g[st], N);
        }
    }
}

// Round 14
// 901.101 us; speedup vs baseline: 1.3205x; 1.0110x over previous
//
#include <hip/hip_runtime.h>

#define THREADS 256
#define SCAN_CHUNK 2048
#define DT_C 0.2f

__device__ __forceinline__ unsigned pack_bf16(float x, float y) {
    unsigned xb = __float_as_uint(x);
    unsigned yb = __float_as_uint(y);
    xb = (xb + 0x7fffu + ((xb >> 16) & 1u)) >> 16;
    yb = (yb + 0x7fffu + ((yb >> 16) & 1u)) >> 16;
    return xb | (yb << 16);
}
__device__ __forceinline__ float lo16(unsigned u) { return __uint_as_float(u << 16); }
__device__ __forceinline__ float hi16(unsigned u) { return __uint_as_float(u & 0xffff0000u); }

// ---------------- CSR build ----------------

__global__ void count_deg_kernel(const int* __restrict__ ei, int E,
                                 int* __restrict__ deg_r, int* __restrict__ deg_c) {
    int e = blockIdx.x * blockDim.x + threadIdx.x;
    if (e < E) {
        atomicAdd(&deg_r[ei[e]], 1);
        atomicAdd(&deg_c[ei[e + E]], 1);
    }
}

__global__ void scan_phase1(const int* __restrict__ deg, int n, int* __restrict__ bsums) {
    int base = blockIdx.x * SCAN_CHUNK;
    int sum = 0;
    for (int i = threadIdx.x; i < SCAN_CHUNK; i += THREADS) {
        int idx = base + i;
        if (idx < n) sum += deg[idx];
    }
    __shared__ int wsum[4];
    int lane = threadIdx.x & 63, wid = threadIdx.x >> 6;
    for (int off = 32; off; off >>= 1) sum += __shfl_down(sum, off);
    if (lane == 0) wsum[wid] = sum;
    __syncthreads();
    if (threadIdx.x == 0)
        bsums[blockIdx.x] = wsum[0] + wsum[1] + wsum[2] + wsum[3];
}

__global__ void scan_phase2(int* __restrict__ bsums, int nb,
                            int* __restrict__ row_ptr, int N, int E) {
    if (blockIdx.x == 0 && threadIdx.x == 0) {
        int acc = 0;
        for (int b = 0; b < nb; ++b) { int v = bsums[b]; bsums[b] = acc; acc += v; }
        row_ptr[N] = E;
    }
}

__global__ void scan_phase3(const int* __restrict__ deg, int n, const int* __restrict__ bsums,
                            int* __restrict__ row_ptr, int* __restrict__ cur_f,
                            int* __restrict__ cur_b) {
    int base = blockIdx.x * SCAN_CHUNK;
    int tbase = base + threadIdx.x * 8;
    int my[8]; int s = 0;
#pragma unroll
    for (int j = 0; j < 8; ++j) { int idx = tbase + j; my[j] = (idx < n) ? deg[idx] : 0; s += my[j]; }
    int lane = threadIdx.x & 63, wid = threadIdx.x >> 6;
    int v = s;
    for (int off = 1; off < 64; off <<= 1) { int t = __shfl_up(v, off); if (lane >= off) v += t; }
    __shared__ int wsum[4];
    if (lane == 63) wsum[wid] = v;
    __syncthreads();
    int woff = 0;
    for (int w = 0; w < wid; ++w) woff += wsum[w];
    int acc = bsums[blockIdx.x] + woff + (v - s);
#pragma unroll
    for (int j = 0; j < 8; ++j) {
        int idx = tbase + j;
        if (idx < n) { row_ptr[idx] = acc; cur_f[idx] = acc; cur_b[idx] = acc + my[j]; }
        acc += my[j];
    }
}

// dr = deg_r^-1/2, dc = deg_c^-1/2, s1 = dr*dc
__global__ void make_dinv(const int* __restrict__ deg_r, const int* __restrict__ deg_c,
                          float* __restrict__ dr, float* __restrict__ dc,
                          float* __restrict__ s1, int n) {
    int i = blockIdx.x * blockDim.x + threadIdx.x;
    if (i < n) {
        int ra = deg_r[i];
        float a = ra > 0 ? rsqrtf((float)ra) : 0.f;
        int cb = deg_c[i];
        float b = cb > 0 ? rsqrtf((float)cb) : 0.f;
        dr[i] = a; dc[i] = b; s1[i] = a * b;
    }
}

// Partitioned scatter: masked edges from the row front, unmasked from the back.
// cur_f[r] ends as the split point.
__global__ void build_csr_kernel(const int* __restrict__ ei, int E,
                                 const int* __restrict__ mask,
                                 int* __restrict__ cur_f, int* __restrict__ cur_b,
                                 int* __restrict__ colv) {
    int e = blockIdx.x * blockDim.x + threadIdx.x;
    if (e < E) {
        int r = ei[e], c = ei[e + E];
        int p;
        if (mask[c]) p = atomicAdd(&cur_f[r], 1);
        else         p = atomicSub(&cur_b[r], 1) - 1;
        colv[p] = c;
    }
}

// ---------------- init: out[0] = r0 ; xb = bf16(dc .* r0) ----------------

__global__ void init_kernel(const float* __restrict__ r0, float* __restrict__ out0,
                            const float* __restrict__ dc,
                            unsigned* __restrict__ xb, int n4) {
    int i = blockIdx.x * blockDim.x + threadIdx.x;
    int stride = gridDim.x * blockDim.x;
    const float4* r4 = (const float4*)r0;
    float4* o4 = (float4*)out0;
    for (; i < n4; i += stride) {
        float4 a = r4[i];
        o4[i] = a;
        float w = dc[i >> 4];   // 16 float4s per node
        xb[2 * i]     = pack_bf16(w * a.x, w * a.y);
        xb[2 * i + 1] = pack_bf16(w * a.z, w * a.w);
    }
}

// ---------------- gather level: NB edges, fully unrolled -> registers ----------------

template <int NB>
__device__ __forceinline__ void accum_level(const int* __restrict__ cols, int j,
                                            const uint2* __restrict__ src, int ql,
                                            float& a0, float& a1, float& a2, float& a3) {
    int cc[NB];
#pragma unroll
    for (int t = 0; t < NB; ++t) cc[t] = cols[j + t];
    uint2 uu[NB];
#pragma unroll
    for (int t = 0; t < NB; ++t) uu[t] = src[(size_t)cc[t] * 16 + ql];
#pragma unroll
    for (int t = 0; t < NB; ++t) {
        a0 += lo16(uu[t].x);  a1 += hi16(uu[t].x);
        a2 += lo16(uu[t].y);  a3 += hi16(uu[t].y);
    }
}

// ---------------- SpMM hop 1 ----------------
// FOUR rows per wave: each 16-lane quarter owns one row (16 lanes x uint2 =
// one full 128B bf16 feature row per edge). 16-edge main level issues 16
// independent gathers -> 128 lines (8KB) in flight per wave, 2x round 13.
// No cross-lane reduction needed: each quarter's accumulator is complete.
// Gathers bf16(dc .* x) over the masked front segment; t1b = bf16(s1*sum).

__global__ __launch_bounds__(256) void spmm_h1(const int* __restrict__ row_ptr,
                                               const int* __restrict__ split,
                                               const int* __restrict__ cols,
                                               const float* __restrict__ s1,
                                               const unsigned* __restrict__ xb,
                                               unsigned* __restrict__ t1b, int n) {
    int l = threadIdx.x & 63, ql = l & 15;
    int row = blockIdx.x * 16 + (threadIdx.x >> 6) * 4 + (l >> 4);
    if (row >= n) return;
    int s = row_ptr[row], e = split[row];
    const uint2* x2 = (const uint2*)xb;
    float a0 = 0.f, a1 = 0.f, a2 = 0.f, a3 = 0.f;
    int j = s;
    for (; j + 15 < e; j += 16) accum_level<16>(cols, j, x2, ql, a0, a1, a2, a3);
    if (j + 7 < e) { accum_level<8>(cols, j, x2, ql, a0, a1, a2, a3); j += 8; }
    if (j + 3 < e) { accum_level<4>(cols, j, x2, ql, a0, a1, a2, a3); j += 4; }
    if (j + 1 < e) { accum_level<2>(cols, j, x2, ql, a0, a1, a2, a3); j += 2; }
    if (j < e)     { accum_level<1>(cols, j, x2, ql, a0, a1, a2, a3); }
    float w = s1[row];
    ((uint2*)t1b)[(size_t)row * 16 + ql] =
        make_uint2(pack_bf16(w * a0, w * a1), pack_bf16(w * a2, w * a3));
}

// ---------------- SpMM hop 2 + fused Taylor epilogue ----------------
// Four rows per wave, same engine over the FULL segment; k = -dr*a.
// ST==0 (first): rn = r + g*k ; xb = bf16(dc*k) = bf16(-s1*a)  [masked rows only]
// ST==3 (last):  rn += g*k    ; xb = bf16(dc*rn)               [masked rows only]

template <int ST>
__global__ __launch_bounds__(256) void spmm_h2(const int* __restrict__ row_ptr,
                                               const int* __restrict__ cols,
                                               const float* __restrict__ dr_arr,
                                               const float* __restrict__ dc_arr,
                                               const float* __restrict__ s1,
                                               const int* __restrict__ msk,
                                               const unsigned* __restrict__ t1b,
                                               const float* __restrict__ r_prev,
                                               float* __restrict__ rn,
                                               unsigned* __restrict__ xb,
                                               float g, int n) {
    int l = threadIdx.x & 63, ql = l & 15;
    int row = blockIdx.x * 16 + (threadIdx.x >> 6) * 4 + (l >> 4);
    if (row >= n) return;
    int s = row_ptr[row], e = row_ptr[row + 1];
    const uint2* t2 = (const uint2*)t1b;
    float a0 = 0.f, a1 = 0.f, a2 = 0.f, a3 = 0.f;
    int j = s;
    for (; j + 15 < e; j += 16) accum_level<16>(cols, j, t2, ql, a0, a1, a2, a3);
    if (j + 7 < e) { accum_level<8>(cols, j, t2, ql, a0, a1, a2, a3); j += 8; }
    if (j + 3 < e) { accum_level<4>(cols, j, t2, ql, a0, a1, a2, a3); j += 4; }
    if (j + 1 < e) { accum_level<2>(cols, j, t2, ql, a0, a1, a2, a3); j += 2; }
    if (j < e)     { accum_level<1>(cols, j, t2, ql, a0, a1, a2, a3); }

    float dr_ = dr_arr[row];
    float k0 = -dr_ * a0, k1 = -dr_ * a1, k2 = -dr_ * a2, k3 = -dr_ * a3;
    size_t idx = (size_t)row * 16 + ql;
    const float4* r4p = (const float4*)r_prev;
    float4* rn4 = (float4*)rn;
    uint2* x2w = (uint2*)xb;
    bool m = msk[row] != 0;   // xb only ever gathered for masked rows
    if (ST == 0) {
        float4 rv = r4p[idx];
        rn4[idx] = make_float4(rv.x + g * k0, rv.y + g * k1,
                               rv.z + g * k2, rv.w + g * k3);
        if (m) {
            float w = s1[row];
            x2w[idx] = make_uint2(pack_bf16(-w * a0, -w * a1),
                                  pack_bf16(-w * a2, -w * a3));   // dc*k
        }
    } else {
        float4 p = rn4[idx];
        p.x += g * k0; p.y += g * k1; p.z += g * k2; p.w += g * k3;
        rn4[idx] = p;
        if (m) {
            float dc_ = dc_arr[row];
            x2w[idx] = make_uint2(pack_bf16(dc_ * p.x, dc_ * p.y),
                                  pack_bf16(dc_ * p.z, dc_ * p.w));
        }
    }
}

// ---------------- host ----------------

extern "C" void kernel_launch(void* const* d_in, const int* in_sizes, int n_in,
                              void* d_out, int out_size, void* d_ws, size_t ws_size,
                              hipStream_t stream) {
    const float* r0  = (const float*)d_in[0];
    const int*   ei  = (const int*)d_in[1];
    const int*   msk = (const int*)d_in[2];
    float* out = (float*)d_out;

    const int N = in_sizes[2];
    const int E = in_sizes[1] / 2;
    const size_t ND = (size_t)N * 64;

    char* ws = (char*)d_ws;
    size_t off = 0;
    auto carve = [&](size_t bytes) -> void* {
        off = (off + 255) & ~(size_t)255;
        void* p = ws + off;
        off += bytes;
        return p;
    };
    int*      deg_r   = (int*)carve((size_t)N * 4);
    int*      deg_c   = (int*)carve((size_t)N * 4);
    int*      row_ptr = (int*)carve((size_t)(N + 1) * 4);
    int*      cur_f   = (int*)carve((size_t)N * 4);   // front cursor -> split point
    int*      cur_b   = (int*)carve((size_t)N * 4);   // back cursor
    int*      bsums   = (int*)carve(1024 * 4);
    float*    dr      = (float*)carve((size_t)N * 4);
    float*    dc      = (float*)carve((size_t)N * 4);
    float*    s1      = (float*)carve((size_t)N * 4);
    int*      colv    = (int*)carve((size_t)E * 4);
    unsigned* xb      = (unsigned*)carve((size_t)N * 32 * 4);
    unsigned* t1b     = (unsigned*)carve((size_t)N * 32 * 4);

    // ---- CSR build (edges partitioned [masked | unmasked] within each row) ----
    hipMemsetAsync(deg_r, 0, (size_t)N * 4, stream);
    hipMemsetAsync(deg_c, 0, (size_t)N * 4, stream);
    int gE = (E + THREADS - 1) / THREADS;
    count_deg_kernel<<<gE, THREADS, 0, stream>>>(ei, E, deg_r, deg_c);
    int nb = (N + SCAN_CHUNK - 1) / SCAN_CHUNK;
    scan_phase1<<<nb, THREADS, 0, stream>>>(deg_r, N, bsums);
    scan_phase2<<<1, 64, 0, stream>>>(bsums, nb, row_ptr, N, E);
    scan_phase3<<<nb, THREADS, 0, stream>>>(deg_r, N, bsums, row_ptr, cur_f, cur_b);
    make_dinv<<<(N + THREADS - 1) / THREADS, THREADS, 0, stream>>>(deg_r, deg_c, dr, dc, s1, N);
    build_csr_kernel<<<gE, THREADS, 0, stream>>>(ei, E, msk, cur_f, cur_b, colv);

    // ---- out[0] = r0 ; xb = bf16(dc .* r0) ----
    init_kernel<<<2048, THREADS, 0, stream>>>(r0, out, dc, xb, (int)(ND / 4));

    // ---- 5 steps of degree-2 Taylor: r+ = r + g1*Lr + g2*L^2 r ----
    const float g[2] = {DT_C, DT_C * DT_C / 2.f};
    int gridR = (N + 15) / 16;

    for (int s = 0; s < 5; ++s) {
        const float* r  = out + (size_t)s * ND;
        float*       rn = out + (size_t)(s + 1) * ND;
        for (int st = 0; st < 2; ++st) {
            spmm_h1<<<gridR, THREADS, 0, stream>>>(row_ptr, cur_f, colv, s1, xb, t1b, N);
            if (st == 0)
                spmm_h2<0><<<gridR, THREADS, 0, stream>>>(row_ptr, colv, dr, dc, s1, msk, t1b, r, rn, xb, g[st], N);
            else
                spmm_h2<3><<<gridR, THREADS, 0, stream>>>(row_ptr, colv, dr, dc, s1, msk, t1b, r, rn, xb, g[st], N);
        }
    }
}